// Round 2
// baseline (779.768 us; speedup 1.0000x reference)
//
#include <hip/hip_runtime.h>

#define DIM 1024
#define HID 1536
#define TT 4096
#define NB 4
#define KCONV 4
#define MROWS (NB * TT)  // 16384
#define NC 32            // scan chunks
#define CH (TT / NC)     // 128

typedef unsigned short u16;
typedef short bf16x8 __attribute__((ext_vector_type(8)));
typedef float f32x4 __attribute__((ext_vector_type(4)));

__device__ __forceinline__ u16 f2bf(float f) {
  union { float f; unsigned u; } v; v.f = f;
  unsigned r = (v.u + 0x7fffu + ((v.u >> 16) & 1u)) >> 16;
  return (u16)r;
}
__device__ __forceinline__ float bf2f(u16 h) {
  union { unsigned u; float f; } v; v.u = ((unsigned)h) << 16;
  return v.f;
}

// ---------------- fp32 -> bf16 convert (4 elems/thread) ----------------
__global__ void cvt_bf16(const float* __restrict__ in, u16* __restrict__ out, int n4) {
  int i = blockIdx.x * blockDim.x + threadIdx.x;
  if (i < n4) {
    float4 v = reinterpret_cast<const float4*>(in)[i];
    ushort4 o;
    o.x = f2bf(v.x); o.y = f2bf(v.y); o.z = f2bf(v.z); o.w = f2bf(v.w);
    reinterpret_cast<ushort4*>(out)[i] = o;
  }
}

// ---------------- bf16 NT GEMM: C[M,N] = A[M,K] * B[N,K]^T ----------------
// m97 structure: 128x128 tile, BK=32, 4 waves, global_load_lds(16B), 16x16x32 MFMA.
#define AS1q __attribute__((address_space(1)))
#define AS3q __attribute__((address_space(3)))
__device__ __forceinline__ void gl_lds16(const u16* g, u16* l) {
  __builtin_amdgcn_global_load_lds((const AS1q void*)g, (AS3q void*)l, 16, 0, 0);
}

// EPI=0: fp32 store to C (ldc=Nn). EPI=1: bf16 split store at column HID -> O0 | O1.
template <int EPI>
__global__ __launch_bounds__(256) void gemm_nt(
    const u16* __restrict__ A, const u16* __restrict__ B,
    float* __restrict__ C, u16* __restrict__ O0, u16* __restrict__ O1,
    int M, int Nn, int K) {
  __shared__ u16 As[128 * 32];
  __shared__ u16 Bs[128 * 32];
  const int tid = threadIdx.x;
  const int l = tid & 63;
  const int w = tid >> 6;
  const int tileM = blockIdx.y * 128;
  const int tileN = blockIdx.x * 128;

  // staging: wave w stages rows [32w, 32w+32) of both tiles; lane l -> row +l/4, col8 (l&3)
  const u16* ga0 = A + (size_t)(tileM + w * 32 + (l >> 2)) * K + (l & 3) * 8;
  const u16* ga1 = ga0 + 16 * (size_t)K;
  const u16* gb0 = B + (size_t)(tileN + w * 32 + (l >> 2)) * K + (l & 3) * 8;
  const u16* gb1 = gb0 + 16 * (size_t)K;
  u16* la0 = &As[w * 1024];
  u16* la1 = &As[w * 1024 + 512];
  u16* lb0 = &Bs[w * 1024];
  u16* lb1 = &Bs[w * 1024 + 512];

  const int wm = (w >> 1) * 64, wn = (w & 1) * 64;
  const int arow = l & 15;
  const int acol = (l >> 4) * 8;

  f32x4 acc[4][4] = {};

  for (int k0 = 0; k0 < K; k0 += 32) {
    __syncthreads();  // previous compute done before LDS overwrite
    gl_lds16(ga0, la0); gl_lds16(ga1, la1);
    gl_lds16(gb0, lb0); gl_lds16(gb1, lb1);
    ga0 += 32; ga1 += 32; gb0 += 32; gb1 += 32;
    __syncthreads();  // compiler emits vmcnt(0) before barrier -> staging visible

    bf16x8 a[4], b[4];
#pragma unroll
    for (int mi = 0; mi < 4; mi++)
      a[mi] = *reinterpret_cast<const bf16x8*>(&As[(wm + mi * 16 + arow) * 32 + acol]);
#pragma unroll
    for (int ni = 0; ni < 4; ni++)
      b[ni] = *reinterpret_cast<const bf16x8*>(&Bs[(wn + ni * 16 + arow) * 32 + acol]);
#pragma unroll
    for (int mi = 0; mi < 4; mi++)
#pragma unroll
      for (int ni = 0; ni < 4; ni++)
        acc[mi][ni] = __builtin_amdgcn_mfma_f32_16x16x32_bf16(a[mi], b[ni], acc[mi][ni], 0, 0, 0);
  }

  // C/D layout (m89-verified): col = lane&15, row = (lane>>4)*4 + reg
  const int r0 = tileM + wm + (l >> 4) * 4;
  const int c0 = tileN + wn + (l & 15);
  if (EPI == 0) {
#pragma unroll
    for (int mi = 0; mi < 4; mi++)
#pragma unroll
      for (int ni = 0; ni < 4; ni++)
#pragma unroll
        for (int r = 0; r < 4; r++)
          C[(size_t)(r0 + mi * 16 + r) * Nn + (c0 + ni * 16)] = acc[mi][ni][r];
  } else {
    u16* dst = (tileN < HID) ? O0 : O1;
    const int cb = (tileN < HID) ? 0 : HID;
#pragma unroll
    for (int mi = 0; mi < 4; mi++)
#pragma unroll
      for (int ni = 0; ni < 4; ni++)
#pragma unroll
        for (int r = 0; r < 4; r++)
          dst[(size_t)(r0 + mi * 16 + r) * HID + (c0 + ni * 16 - cb)] = f2bf(acc[mi][ni][r]);
  }
}

// ---------------- causal depthwise conv1d (K=4, left pad 3) ----------------
__global__ void conv1d_k(const u16* __restrict__ u, const float* __restrict__ w,
                         const float* __restrict__ b, u16* __restrict__ uc) {
  int idx = blockIdx.x * blockDim.x + threadIdx.x;  // over MROWS*HID
  int h = idx % HID;
  int r = idx / HID;
  int t = r % TT;
  float acc = b[h];
#pragma unroll
  for (int k = 0; k < KCONV; k++) {
    int ts = t - (KCONV - 1) + k;
    if (ts >= 0) acc += bf2f(u[(size_t)(r - (KCONV - 1) + k) * HID + h]) * w[h * KCONV + k];
  }
  uc[idx] = f2bf(acc);
}

// ---------------- RG-LRU scan, chunked 3-phase ----------------
__global__ void scan_phase1(const u16* __restrict__ fbuf, const u16* __restrict__ ibuf,
                            const u16* __restrict__ ubuf, const float* __restrict__ fb,
                            const float* __restrict__ bg,
                            float* __restrict__ Ac, float* __restrict__ Bc) {
  int tid = blockIdx.x * blockDim.x + threadIdx.x;  // NB*HID*NC
  int h = tid % HID;
  int nc = tid / HID;
  int n = nc % NB;
  int c = nc / NB;
  float c8 = 8.0f * log1pf(expf(fb[h]));
  float bgf = bg[h];
  float bgi = bg[HID + h];
  float aprod = 1.0f, hloc = 0.0f;
  size_t base = ((size_t)n * TT + (size_t)c * CH) * HID + h;
  for (int t = 0; t < CH; t++) {
    size_t ix = base + (size_t)t * HID;
    float f = bf2f(fbuf[ix]) + bgf;
    float sf = 1.0f / (1.0f + expf(-f));
    float al = expf(-c8 * sf);
    float be = sqrtf(1.0f - al * al + 1e-6f);
    float xi = bf2f(ibuf[ix]) + bgi;
    float si = 1.0f / (1.0f + expf(-xi));
    float xt = be * si * bf2f(ubuf[ix]);
    hloc = al * hloc + xt;
    aprod *= al;
  }
  size_t ci = ((size_t)c * NB + n) * HID + h;
  Ac[ci] = aprod;
  Bc[ci] = hloc;
}

__global__ void scan_phase2(const float* __restrict__ Ac, const float* __restrict__ Bc,
                            float* __restrict__ Carry) {
  int tid = blockIdx.x * blockDim.x + threadIdx.x;  // NB*HID
  int h = tid % HID;
  int n = tid / HID;
  float carry = 0.f;
  for (int c = 0; c < NC; c++) {
    size_t ci = ((size_t)c * NB + n) * HID + h;
    Carry[ci] = carry;
    carry = Ac[ci] * carry + Bc[ci];
  }
}

__global__ void scan_phase3(const u16* __restrict__ fbuf, const u16* __restrict__ ibuf,
                            const u16* __restrict__ ubuf, const u16* __restrict__ gbuf,
                            const float* __restrict__ fb, const float* __restrict__ bg,
                            const float* __restrict__ Carry, u16* __restrict__ gh) {
  int tid = blockIdx.x * blockDim.x + threadIdx.x;  // NB*HID*NC
  int h = tid % HID;
  int nc = tid / HID;
  int n = nc % NB;
  int c = nc / NB;
  float c8 = 8.0f * log1pf(expf(fb[h]));
  float bgf = bg[h];
  float bgi = bg[HID + h];
  size_t ci = ((size_t)c * NB + n) * HID + h;
  float hcur = Carry[ci];
  size_t base = ((size_t)n * TT + (size_t)c * CH) * HID + h;
  for (int t = 0; t < CH; t++) {
    size_t ix = base + (size_t)t * HID;
    float f = bf2f(fbuf[ix]) + bgf;
    float sf = 1.0f / (1.0f + expf(-f));
    float al = expf(-c8 * sf);
    float be = sqrtf(1.0f - al * al + 1e-6f);
    float xi = bf2f(ibuf[ix]) + bgi;
    float si = 1.0f / (1.0f + expf(-xi));
    float xt = be * si * bf2f(ubuf[ix]);
    hcur = al * hcur + xt;
    float g = bf2f(gbuf[ix]);
    float gl = 0.5f * g * (1.0f + erff(g * 0.70710678118f));
    gh[ix] = f2bf(gl * hcur);
  }
}

// ---------------- launch ----------------
extern "C" void kernel_launch(void* const* d_in, const int* in_sizes, int n_in,
                              void* d_out, int out_size, void* d_ws, size_t ws_size,
                              hipStream_t stream) {
  const float* x  = (const float*)d_in[0];
  const float* Wi = (const float*)d_in[1];
  const float* cw = (const float*)d_in[2];
  const float* cb = (const float*)d_in[3];
  const float* Wg = (const float*)d_in[4];
  const float* bg = (const float*)d_in[5];
  const float* fb = (const float*)d_in[6];
  const float* Wo = (const float*)d_in[7];
  float* out = (float*)d_out;

  // ---- workspace budget: exactly 253,755,392 bytes (all sizes %256==0) ----
  const size_t SZ_XBF  = (size_t)MROWS * DIM * 2;      // 33,554,432
  const size_t SZ_WI   = (size_t)2 * HID * DIM * 2;    //  6,291,456
  const size_t SZ_WG   = (size_t)2 * HID * HID * 2;    //  9,437,184
  const size_t SZ_WO   = (size_t)DIM * HID * 2;        //  3,145,728
  const size_t SZ_ACT  = (size_t)MROWS * HID * 2;      // 50,331,648
  const size_t REQUIRED = SZ_XBF + SZ_WI + SZ_WG + SZ_WO + 4 * SZ_ACT;
  if (ws_size < REQUIRED) return;  // diagnostic: clean absmax fail => ws too small

  char* p = (char*)d_ws;
  auto alloc = [&](size_t bytes) { char* q = p; p += bytes; return q; };
  u16* x_bf   = (u16*)alloc(SZ_XBF);
  u16* Wi_bf  = (u16*)alloc(SZ_WI);
  u16* Wg_bf  = (u16*)alloc(SZ_WG);
  u16* Wo_bf  = (u16*)alloc(SZ_WO);
  u16* u_bf   = (u16*)alloc(SZ_ACT);   // u after GEMM1; reused as gh after conv
  u16* uc_bf  = (u16*)alloc(SZ_ACT);   // conv output
  u16* fg0_bf = (u16*)alloc(SZ_ACT);   // forget logits
  u16* fg1_bf = (u16*)alloc(SZ_ACT);   // input-gate logits
  u16* gh_bf  = u_bf;                  // alias: u dead after conv1d

  // ---- carve gate + scan state out of d_out (dead until final GEMM) ----
  u16* gate_bf = (u16*)d_out;                               // 50,331,648 B
  float* Ac    = (float*)((char*)d_out + SZ_ACT);           //    786,432 B
  float* Bc    = Ac + (size_t)NC * NB * HID;                //    786,432 B
  float* Carry = Bc + (size_t)NC * NB * HID;                //    786,432 B
  // total d_out usage: 52,690,944 < 67,108,864 bytes

  cvt_bf16<<<(MROWS * DIM / 4) / 256, 256, 0, stream>>>(x, x_bf, MROWS * DIM / 4);
  cvt_bf16<<<(2 * HID * DIM / 4) / 256, 256, 0, stream>>>(Wi, Wi_bf, 2 * HID * DIM / 4);
  cvt_bf16<<<(2 * HID * HID / 4) / 256, 256, 0, stream>>>(Wg, Wg_bf, 2 * HID * HID / 4);
  cvt_bf16<<<(DIM * HID / 4) / 256, 256, 0, stream>>>(Wo, Wo_bf, DIM * HID / 4);

  // gi = x * Wi^T -> gate | u
  gemm_nt<1><<<dim3(2 * HID / 128, MROWS / 128), 256, 0, stream>>>(
      x_bf, Wi_bf, nullptr, gate_bf, u_bf, MROWS, 2 * HID, DIM);
  // causal depthwise conv
  conv1d_k<<<(MROWS * HID) / 256, 256, 0, stream>>>(u_bf, cw, cb, uc_bf);
  // fg = uc * Wg^T -> forget | inp
  gemm_nt<1><<<dim3(2 * HID / 128, MROWS / 128), 256, 0, stream>>>(
      uc_bf, Wg_bf, nullptr, fg0_bf, fg1_bf, MROWS, 2 * HID, HID);
  // RG-LRU scan + gelu(gate)*h  (gh overwrites u_bf; gate/Ac/Bc/Carry live in d_out)
  scan_phase1<<<(NB * HID * NC) / 256, 256, 0, stream>>>(fg0_bf, fg1_bf, uc_bf, fb, bg, Ac, Bc);
  scan_phase2<<<(NB * HID) / 256, 256, 0, stream>>>(Ac, Bc, Carry);
  scan_phase3<<<(NB * HID * NC) / 256, 256, 0, stream>>>(fg0_bf, fg1_bf, uc_bf, gate_bf, fb, bg, Carry, gh_bf);
  // out = gh * Wo^T (fp32) -- overwrites all of d_out last
  gemm_nt<0><<<dim3(DIM / 128, MROWS / 128), 256, 0, stream>>>(
      gh_bf, Wo_bf, out, nullptr, nullptr, MROWS, DIM, HID);
}